// Round 5
// baseline (180.820 us; speedup 1.0000x reference)
//
#include <hip/hip_runtime.h>
#include <math.h>

#define BB 8
#define NN 100
#define KK 20
#define DD 256
#define MM 2000                    // NN*KK anchors per batch
#define MP 2048                    // padded rows per batch
#define NTILE 136                  // upper-tri 128x128 tile pairs in 16x16 grid
#define TINV 10.0f                 // 1/TEMP
#define LOSS_SCALE 1.953125e-7f    // ALPHA / (B_NORM*N*K*D) = 0.1/512000

typedef __bf16 bf16x8 __attribute__((ext_vector_type(8)));
typedef float floatx4 __attribute__((ext_vector_type(4)));
typedef __attribute__((address_space(1))) const ushort GUshort;
typedef __attribute__((address_space(3))) ushort LUshort;

__device__ __forceinline__ ushort f2bf(float f) {
    unsigned int u = __float_as_uint(f);
    u += 0x7fffu + ((u >> 16) & 1u);   // round-to-nearest-even
    return (ushort)(u >> 16);
}

// ---------------- kernel 1: normalize+convert to bf16, zero-pad, zero accumulators ----------------
__global__ void norm_bf16(const float* __restrict__ x, ushort* __restrict__ xb,
                          float* __restrict__ accbuf, unsigned* __restrict__ counter) {
    // fold accumulator + completion-counter zero-init into this pass
    if (blockIdx.x < 32)
        ((float4*)accbuf)[blockIdx.x * 256 + threadIdx.x] = make_float4(0.f, 0.f, 0.f, 0.f);
    if (blockIdx.x == 0 && threadIdx.x == 0) counter[0] = 0u;

    const int rg = blockIdx.x * 4 + (threadIdx.x >> 6);   // 0..16383
    const int lane = threadIdx.x & 63;
    const int b = rg >> 11;
    const int r = rg & (MP - 1);
    ushort4 outv = make_ushort4(0, 0, 0, 0);
    if (r < MM) {   // wave-uniform branch
        const float4 v = ((const float4*)(x + ((size_t)(b * MM + r)) * DD))[lane];
        float s = v.x * v.x + v.y * v.y + v.z * v.z + v.w * v.w;
        #pragma unroll
        for (int o = 32; o >= 1; o >>= 1) s += __shfl_xor(s, o, 64);
        const float inv = 1.0f / sqrtf(s);
        outv.x = f2bf(v.x * inv);
        outv.y = f2bf(v.y * inv);
        outv.z = f2bf(v.z * inv);
        outv.w = f2bf(v.w * inv);
    }
    ((ushort4*)(xb + (size_t)rg * DD))[lane] = outv;
}

// ---------------- kernel 2: symmetric MFMA Gram + fused exp/intra epilogue + fused finalize ----------------
// Both A and B staged in LDS via global_load_lds(16B), granule-XOR swizzle
// (conflict-free b128 frag reads AND lane-contiguous DMA). XCD-pinned: batch = blk&7,
// so each XCD's L2 holds only its batch's 1 MB xb slice.
__global__ __launch_bounds__(256)
void cl_mfma(const ushort* __restrict__ xb,
             float* __restrict__ denom_g, float* __restrict__ intra_g,
             unsigned* __restrict__ counter, float* __restrict__ out) {
    __shared__ __align__(16) ushort As[128 * 64];
    __shared__ __align__(16) ushort Bs[128 * 64];

    // decode block -> (batch = blk&7 for XCD pinning, upper-tri tile pair)
    const int b = blockIdx.x & 7;
    int rem = blockIdx.x >> 3;    // 0..135
    int ti = 0;
    while (rem >= 16 - ti) { rem -= 16 - ti; ++ti; }
    const int tj = ti + rem;
    const int rbase = ti << 7;
    const int cbase = tj << 7;
    const bool offdiag = (ti != tj);
    const ushort* __restrict__ xbb = xb + (size_t)b * MP * DD;

    const int tid = threadIdx.x;
    const int lane = tid & 63;
    const int w = tid >> 6;
    const int wr = (w >> 1) << 6;   // wave row offset within 128-tile
    const int wc = (w & 1) << 6;    // wave col offset
    const int tx = lane & 15;
    const int tx7 = tx & 7;
    const int quad = lane >> 4;

    // staging lane roles: 8 rows x 8 granule-slots per instruction
    const int srow = lane >> 3;          // row within 8-row chunk
    const int sg = (lane & 7) ^ srow;    // logical granule this slot holds

    floatx4 acc[4][4];
    #pragma unroll
    for (int mt = 0; mt < 4; ++mt)
        #pragma unroll
        for (int nt = 0; nt < 4; ++nt)
            acc[mt][nt] = (floatx4){0.f, 0.f, 0.f, 0.f};

    #pragma unroll 1
    for (int kc = 0; kc < 4; ++kc) {
        __syncthreads();
        #pragma unroll
        for (int q = 0; q < 4; ++q) {
            const int R = ((w << 2) + q) << 3;            // 8-row chunk base
            const size_t koff = (kc << 6) + (sg << 3);
            __builtin_amdgcn_global_load_lds(
                (GUshort*)(xbb + (size_t)(rbase + R + srow) * DD + koff),
                (LUshort*)(As + R * 64), 16, 0, 0);
            __builtin_amdgcn_global_load_lds(
                (GUshort*)(xbb + (size_t)(cbase + R + srow) * DD + koff),
                (LUshort*)(Bs + R * 64), 16, 0, 0);
        }
        __syncthreads();

        #pragma unroll
        for (int ks = 0; ks < 2; ++ks) {
            const int g = (ks << 2) + quad;          // logical granule
            const int gp = (g ^ tx7) << 3;           // swizzled ushort offset
            bf16x8 af[4], bf[4];
            #pragma unroll
            for (int mt = 0; mt < 4; ++mt)
                af[mt] = *(const bf16x8*)(As + (wr + (mt << 4) + tx) * 64 + gp);
            #pragma unroll
            for (int nt = 0; nt < 4; ++nt)
                bf[nt] = *(const bf16x8*)(Bs + (wc + (nt << 4) + tx) * 64 + gp);
            #pragma unroll
            for (int mt = 0; mt < 4; ++mt)
                #pragma unroll
                for (int nt = 0; nt < 4; ++nt)
                    acc[mt][nt] = __builtin_amdgcn_mfma_f32_16x16x32_bf16(af[mt], bf[nt], acc[mt][nt], 0, 0, 0);
        }
    }

    // epilogue. C/D layout: col=lane&15, row=quad*4+reg.
    int colv[4], colcls[4];
    bool colok[4];
    #pragma unroll
    for (int nt = 0; nt < 4; ++nt) {
        const int c = cbase + wc + (nt << 4) + tx;
        colv[nt] = c;
        colok[nt] = c < MM;
        colcls[nt] = c / KK;
    }
    float de_c[4] = {0.f, 0.f, 0.f, 0.f};
    float it_c[4] = {0.f, 0.f, 0.f, 0.f};

    #pragma unroll
    for (int mt = 0; mt < 4; ++mt) {
        #pragma unroll
        for (int i = 0; i < 4; ++i) {
            const int row = rbase + wr + (mt << 4) + (quad << 2) + i;
            const int rcls = row / KK;
            float de = 0.f, it = 0.f;
            #pragma unroll
            for (int nt = 0; nt < 4; ++nt) {
                const float sim = acc[mt][nt][i] * TINV;
                const bool ok = colok[nt] && (colv[nt] != row);
                const float e = ok ? __expf(sim) : 0.0f;
                const float sv = (ok && (colcls[nt] == rcls)) ? sim : 0.0f;
                de += e;
                it += sv;
                de_c[nt] += e;   // col-side (used only when offdiag; padded rows occur only in diag tile 15,15)
                it_c[nt] += sv;
            }
            #pragma unroll
            for (int o = 8; o >= 1; o >>= 1) {
                de += __shfl_xor(de, o, 64);
                it += __shfl_xor(it, o, 64);
            }
            if (tx == 0) {
                atomicAdd(&denom_g[b * MP + row], de);
                atomicAdd(&intra_g[b * MP + row], it);
            }
        }
    }

    if (offdiag) {
        #pragma unroll
        for (int nt = 0; nt < 4; ++nt) {
            de_c[nt] += __shfl_xor(de_c[nt], 16, 64);
            de_c[nt] += __shfl_xor(de_c[nt], 32, 64);
            it_c[nt] += __shfl_xor(it_c[nt], 16, 64);
            it_c[nt] += __shfl_xor(it_c[nt], 32, 64);
        }
        if (quad == 0) {
            #pragma unroll
            for (int nt = 0; nt < 4; ++nt) {
                if (colok[nt]) {
                    atomicAdd(&denom_g[b * MP + colv[nt]], de_c[nt]);
                    atomicAdd(&intra_g[b * MP + colv[nt]], it_c[nt]);
                }
            }
        }
    }

    // ---- fused finalize: last block to finish reduces log(denom) - intra/(K-1) ----
    __shared__ unsigned lastS;
    __shared__ float red[4];
    __threadfence();          // release this thread's atomics (all threads)
    __syncthreads();
    if (tid == 0) {
        const unsigned old = atomicAdd(counter, 1u);
        lastS = (old == (unsigned)(BB * NTILE - 1)) ? 1u : 0u;
    }
    __syncthreads();
    if (lastS) {
        __threadfence();      // acquire
        float s = 0.0f;
        for (int i = tid; i < BB * MM; i += 256) {
            const int bb = i / MM;
            const int r = i - bb * MM;
            // coherent (L1-bypassing) reads via atomic no-op add
            const float dn = atomicAdd(&denom_g[bb * MP + r], 0.0f);
            const float it = atomicAdd(&intra_g[bb * MP + r], 0.0f);
            s += logf(dn) - it * (1.0f / (KK - 1));
        }
        #pragma unroll
        for (int o = 32; o >= 1; o >>= 1) s += __shfl_xor(s, o, 64);
        if ((tid & 63) == 0) red[tid >> 6] = s;
        __syncthreads();
        if (tid == 0) out[0] = (red[0] + red[1] + red[2] + red[3]) * LOSS_SCALE;
    }
}

extern "C" void kernel_launch(void* const* d_in, const int* in_sizes, int n_in,
                              void* d_out, int out_size, void* d_ws, size_t ws_size,
                              hipStream_t stream) {
    const float* x = (const float*)d_in[0];
    float* out = (float*)d_out;
    float* denom_g = (float*)d_ws;                     // 8*2048 floats
    float* intra_g = denom_g + BB * MP;                // 8*2048 floats
    unsigned* counter = (unsigned*)(intra_g + BB * MP);
    ushort* xb = (ushort*)((char*)d_ws + (size_t)2 * BB * MP * sizeof(float) + 256);

    norm_bf16<<<BB * MP / 4, 256, 0, stream>>>(x, xb, denom_g, counter);
    cl_mfma<<<BB * NTILE, 256, 0, stream>>>(xb, denom_g, intra_g, counter, out);
}

// Round 6
// 103.538 us; speedup vs baseline: 1.7464x; 1.7464x over previous
//
#include <hip/hip_runtime.h>
#include <math.h>

#define BB 8
#define NN 100
#define KK 20
#define DD 256
#define MM 2000                    // NN*KK anchors per batch
#define MP 2048                    // padded rows per batch
#define NTILE 136                  // upper-tri 128x128 tile pairs in 16x16 grid
#define TINV 10.0f                 // 1/TEMP
#define LOSS_SCALE 1.953125e-7f    // ALPHA / (B_NORM*N*K*D) = 0.1/512000

typedef __bf16 bf16x8 __attribute__((ext_vector_type(8)));
typedef float floatx4 __attribute__((ext_vector_type(4)));
typedef __attribute__((address_space(1))) const ushort GUshort;
typedef __attribute__((address_space(3))) ushort LUshort;

__device__ __forceinline__ ushort f2bf(float f) {
    unsigned int u = __float_as_uint(f);
    u += 0x7fffu + ((u >> 16) & 1u);   // round-to-nearest-even
    return (ushort)(u >> 16);
}

// ---------------- kernel 1: normalize+convert to bf16, zero-pad, zero accumulators ----------------
__global__ void norm_bf16(const float* __restrict__ x, ushort* __restrict__ xb,
                          float* __restrict__ accbuf, float* __restrict__ out) {
    // fold accumulator + out zero-init into this pass (no memset dispatches)
    if (blockIdx.x < 32)
        ((float4*)accbuf)[blockIdx.x * 256 + threadIdx.x] = make_float4(0.f, 0.f, 0.f, 0.f);
    if (blockIdx.x == 0 && threadIdx.x == 0) out[0] = 0.0f;

    const int rg = blockIdx.x * 4 + (threadIdx.x >> 6);   // 0..16383
    const int lane = threadIdx.x & 63;
    const int b = rg >> 11;
    const int r = rg & (MP - 1);
    ushort4 outv = make_ushort4(0, 0, 0, 0);
    if (r < MM) {   // wave-uniform branch
        const float4 v = ((const float4*)(x + ((size_t)(b * MM + r)) * DD))[lane];
        float s = v.x * v.x + v.y * v.y + v.z * v.z + v.w * v.w;
        #pragma unroll
        for (int o = 32; o >= 1; o >>= 1) s += __shfl_xor(s, o, 64);
        const float inv = 1.0f / sqrtf(s);
        outv.x = f2bf(v.x * inv);
        outv.y = f2bf(v.y * inv);
        outv.z = f2bf(v.z * inv);
        outv.w = f2bf(v.w * inv);
    }
    ((ushort4*)(xb + (size_t)rg * DD))[lane] = outv;
}

// ---------------- kernel 2: symmetric MFMA Gram + fused exp/intra epilogue ----------------
// Both A and B staged in LDS via global_load_lds(16B), granule-XOR swizzle
// (conflict-free b128 frag reads AND lane-contiguous DMA). XCD-pinned: batch = blk&7,
// so each XCD's L2 holds only its batch's 1 MB xb slice (FETCH 33->4 MB, measured R5).
__global__ __launch_bounds__(256)
void cl_mfma(const ushort* __restrict__ xb,
             float* __restrict__ denom_g, float* __restrict__ intra_g) {
    __shared__ __align__(16) ushort As[128 * 64];
    __shared__ __align__(16) ushort Bs[128 * 64];

    // decode block -> (batch = blk&7 for XCD pinning, upper-tri tile pair)
    const int b = blockIdx.x & 7;
    int rem = blockIdx.x >> 3;    // 0..135
    int ti = 0;
    while (rem >= 16 - ti) { rem -= 16 - ti; ++ti; }
    const int tj = ti + rem;
    const int rbase = ti << 7;
    const int cbase = tj << 7;
    const bool offdiag = (ti != tj);
    const ushort* __restrict__ xbb = xb + (size_t)b * MP * DD;

    const int tid = threadIdx.x;
    const int lane = tid & 63;
    const int w = tid >> 6;
    const int wr = (w >> 1) << 6;   // wave row offset within 128-tile
    const int wc = (w & 1) << 6;    // wave col offset
    const int tx = lane & 15;
    const int tx7 = tx & 7;
    const int quad = lane >> 4;

    // staging lane roles: 8 rows x 8 granule-slots per instruction
    const int srow = lane >> 3;          // row within 8-row chunk
    const int sg = (lane & 7) ^ srow;    // logical granule this slot holds

    floatx4 acc[4][4];
    #pragma unroll
    for (int mt = 0; mt < 4; ++mt)
        #pragma unroll
        for (int nt = 0; nt < 4; ++nt)
            acc[mt][nt] = (floatx4){0.f, 0.f, 0.f, 0.f};

    #pragma unroll 1
    for (int kc = 0; kc < 4; ++kc) {
        __syncthreads();
        #pragma unroll
        for (int q = 0; q < 4; ++q) {
            const int R = ((w << 2) + q) << 3;            // 8-row chunk base
            const size_t koff = (kc << 6) + (sg << 3);
            __builtin_amdgcn_global_load_lds(
                (GUshort*)(xbb + (size_t)(rbase + R + srow) * DD + koff),
                (LUshort*)(As + R * 64), 16, 0, 0);
            __builtin_amdgcn_global_load_lds(
                (GUshort*)(xbb + (size_t)(cbase + R + srow) * DD + koff),
                (LUshort*)(Bs + R * 64), 16, 0, 0);
        }
        __syncthreads();

        #pragma unroll
        for (int ks = 0; ks < 2; ++ks) {
            const int g = (ks << 2) + quad;          // logical granule
            const int gp = (g ^ tx7) << 3;           // swizzled ushort offset
            bf16x8 af[4], bf[4];
            #pragma unroll
            for (int mt = 0; mt < 4; ++mt)
                af[mt] = *(const bf16x8*)(As + (wr + (mt << 4) + tx) * 64 + gp);
            #pragma unroll
            for (int nt = 0; nt < 4; ++nt)
                bf[nt] = *(const bf16x8*)(Bs + (wc + (nt << 4) + tx) * 64 + gp);
            #pragma unroll
            for (int mt = 0; mt < 4; ++mt)
                #pragma unroll
                for (int nt = 0; nt < 4; ++nt)
                    acc[mt][nt] = __builtin_amdgcn_mfma_f32_16x16x32_bf16(af[mt], bf[nt], acc[mt][nt], 0, 0, 0);
        }
    }

    // epilogue. C/D layout: col=lane&15, row=quad*4+reg.
    int colv[4], colcls[4];
    bool colok[4];
    #pragma unroll
    for (int nt = 0; nt < 4; ++nt) {
        const int c = cbase + wc + (nt << 4) + tx;
        colv[nt] = c;
        colok[nt] = c < MM;
        colcls[nt] = c / KK;
    }
    float de_c[4] = {0.f, 0.f, 0.f, 0.f};
    float it_c[4] = {0.f, 0.f, 0.f, 0.f};

    #pragma unroll
    for (int mt = 0; mt < 4; ++mt) {
        #pragma unroll
        for (int i = 0; i < 4; ++i) {
            const int row = rbase + wr + (mt << 4) + (quad << 2) + i;
            const int rcls = row / KK;
            float de = 0.f, it = 0.f;
            #pragma unroll
            for (int nt = 0; nt < 4; ++nt) {
                const float sim = acc[mt][nt][i] * TINV;
                const bool ok = colok[nt] && (colv[nt] != row);
                const float e = ok ? __expf(sim) : 0.0f;
                const float sv = (ok && (colcls[nt] == rcls)) ? sim : 0.0f;
                de += e;
                it += sv;
                de_c[nt] += e;   // col-side (used only when offdiag)
                it_c[nt] += sv;
            }
            #pragma unroll
            for (int o = 8; o >= 1; o >>= 1) {
                de += __shfl_xor(de, o, 64);
                it += __shfl_xor(it, o, 64);
            }
            if (tx == 0) {
                atomicAdd(&denom_g[b * MP + row], de);
                atomicAdd(&intra_g[b * MP + row], it);
            }
        }
    }

    if (offdiag) {
        #pragma unroll
        for (int nt = 0; nt < 4; ++nt) {
            de_c[nt] += __shfl_xor(de_c[nt], 16, 64);
            de_c[nt] += __shfl_xor(de_c[nt], 32, 64);
            it_c[nt] += __shfl_xor(it_c[nt], 16, 64);
            it_c[nt] += __shfl_xor(it_c[nt], 32, 64);
        }
        if (quad == 0) {
            #pragma unroll
            for (int nt = 0; nt < 4; ++nt) {
                if (colok[nt]) {
                    atomicAdd(&denom_g[b * MP + colv[nt]], de_c[nt]);
                    atomicAdd(&intra_g[b * MP + colv[nt]], it_c[nt]);
                }
            }
        }
    }
}

// ---------------- kernel 3: log + final reduction, parallel + atomic ----------------
__global__ void finalize_kernel(const float* __restrict__ denom_g,
                                const float* __restrict__ intra_g,
                                float* __restrict__ out) {
    const int i = blockIdx.x * 256 + threadIdx.x;
    float s = 0.0f;
    if (i < BB * MM) {
        const int b = i / MM;
        const int r = i - b * MM;
        s = logf(denom_g[b * MP + r]) - intra_g[b * MP + r] * (1.0f / (KK - 1));
    }
    #pragma unroll
    for (int o = 32; o >= 1; o >>= 1) s += __shfl_xor(s, o, 64);
    __shared__ float red[4];
    if ((threadIdx.x & 63) == 0) red[threadIdx.x >> 6] = s;
    __syncthreads();
    if (threadIdx.x == 0)
        atomicAdd(out, (red[0] + red[1] + red[2] + red[3]) * LOSS_SCALE);
}

extern "C" void kernel_launch(void* const* d_in, const int* in_sizes, int n_in,
                              void* d_out, int out_size, void* d_ws, size_t ws_size,
                              hipStream_t stream) {
    const float* x = (const float*)d_in[0];
    float* out = (float*)d_out;
    float* denom_g = (float*)d_ws;                 // 8*2048 floats
    float* intra_g = denom_g + BB * MP;            // 8*2048 floats
    ushort* xb = (ushort*)(intra_g + BB * MP);     // 8*2048*256 bf16 = 8 MB

    norm_bf16<<<BB * MP / 4, 256, 0, stream>>>(x, xb, denom_g, out);
    cl_mfma<<<BB * NTILE, 256, 0, stream>>>(xb, denom_g, intra_g);
    finalize_kernel<<<(BB * MM + 255) / 256, 256, 0, stream>>>(denom_g, intra_g, out);
}